// Round 5
// baseline (369.014 us; speedup 1.0000x reference)
//
#include <hip/hip_runtime.h>
#include <cstdint>
#include <cstddef>

#define DEVINL __device__ __forceinline__

typedef __attribute__((ext_vector_type(8))) short short8v;   // 8 bf16 (4 VGPRs)
typedef __attribute__((ext_vector_type(4))) float f32x4;

static constexpr int CB   = 4;       // batches
static constexpr int CC   = 256;     // channels
static constexpr int NN   = 2304;    // H*W
static constexpr int RALL = CB * NN; // 9216

// ---- bf16 helpers (bit-level, RNE; avoids hip_bf16 API drift) ----
DEVINL uint16_t f2b(float f) {
    uint32_t u = __builtin_bit_cast(uint32_t, f);
    u = (u + 0x7FFFu + ((u >> 16) & 1u)) >> 16;
    return (uint16_t)u;
}
DEVINL float b2f(uint16_t u) {
    return __builtin_bit_cast(float, (uint32_t)u << 16);
}

// ---------------------------------------------------------------------------
// Transpose+convert: x[b][c][n] fp32 -> Xt[mod][b*N+n][c] bf16
// ---------------------------------------------------------------------------
__global__ __launch_bounds__(1024)
void transpose_k(const float* __restrict__ x0, const float* __restrict__ x1,
                 const float* __restrict__ x2, uint16_t* __restrict__ Xt) {
    int mod = blockIdx.z >> 2;
    int b   = blockIdx.z & 3;
    const float* x = (mod == 0) ? x0 : ((mod == 1) ? x1 : x2);
    __shared__ float tile[32][33];
    int n0 = blockIdx.x * 32, c0 = blockIdx.y * 32;
    int tx = threadIdx.x, ty = threadIdx.y;
    tile[ty][tx] = x[((size_t)b * CC + c0 + ty) * NN + n0 + tx];
    __syncthreads();
    float v = tile[tx][ty]; // = x[b][c0+tx][n0+ty]
    Xt[(size_t)mod * RALL * CC + ((size_t)b * NN + n0 + ty) * CC + c0 + tx] = f2b(v);
}

// ---------------------------------------------------------------------------
// Pack 11 weight matrices (fp32->bf16, row-major kept) + 11 biases (fp32)
// order: wq0,wk0,wv0,wq1,wk1,wv1,wq2,wk2,wv2,wg,wo
// ---------------------------------------------------------------------------
struct PackPtrs { const float* w[11]; const float* bsrc[11]; };

__global__ __launch_bounds__(256)
void pack_k(PackPtrs pp, uint16_t* __restrict__ Wbf, float* __restrict__ Bpk) {
    int j = blockIdx.y;
    if (blockIdx.x == 32) {
        Bpk[j * 256 + threadIdx.x] = pp.bsrc[j][threadIdx.x];
    } else {
        int base = blockIdx.x * 2048 + threadIdx.x * 8;
        const float* src = pp.w[j] + base;
        uint16_t* dst = Wbf + (size_t)j * 65536 + base;
        #pragma unroll
        for (int i = 0; i < 8; i++) dst[i] = f2b(src[i]);
    }
}

// ---------------------------------------------------------------------------
// Ks[a] = Kt[m1] + Kt[m2]   (a=0: kd+kt ; a=1: kr+kt ; a=2: kr+kd)
// ---------------------------------------------------------------------------
__global__ __launch_bounds__(256)
void ksum_k(const uint16_t* __restrict__ Kt, uint16_t* __restrict__ Ks) {
    int a = blockIdx.y;
    int m1 = (a == 0) ? 2 : 0;
    int m2 = (a == 2) ? 2 : 1;
    size_t idx = ((size_t)blockIdx.x * 256 + threadIdx.x) * 4;
    const uint16_t* p1 = Kt + (size_t)m1 * RALL * CC + idx;
    const uint16_t* p2 = Kt + (size_t)m2 * RALL * CC + idx;
    uint16_t* pd = Ks + (size_t)a * RALL * CC + idx;
    #pragma unroll
    for (int i = 0; i < 4; i++) pd[i] = f2b(b2f(p1[i]) + b2f(p2[i]));
}

// ---------------------------------------------------------------------------
// fused = gated[0] + gated[1] + gated[2]   (bf16)
// ---------------------------------------------------------------------------
__global__ __launch_bounds__(256)
void fuse_k(const uint16_t* __restrict__ gated, uint16_t* __restrict__ fused) {
    size_t idx = ((size_t)blockIdx.x * 256 + threadIdx.x) * 4;
    #pragma unroll
    for (int i = 0; i < 4; i++) {
        float v = b2f(gated[idx + i])
                + b2f(gated[(size_t)RALL * CC + idx + i])
                + b2f(gated[(size_t)2 * RALL * CC + idx + i]);
        fused[idx + i] = f2b(v);
    }
}

// ---------------------------------------------------------------------------
// Row softmax over S[row][0..2304) bf16, in place. One block per row.
// ---------------------------------------------------------------------------
__global__ __launch_bounds__(256)
void softmax_k(uint16_t* __restrict__ S) {
    size_t row = (size_t)blockIdx.y * NN + blockIdx.x;
    uint16_t* p = S + row * NN;
    int t = threadIdx.x;
    float v[9];
    float m = -1e30f;
    #pragma unroll
    for (int i = 0; i < 9; i++) { v[i] = b2f(p[t + i * 256]); m = fmaxf(m, v[i]); }
    #pragma unroll
    for (int o = 32; o >= 1; o >>= 1) m = fmaxf(m, __shfl_xor(m, o));
    __shared__ float rm[4];
    __shared__ float rs[4];
    int w = t >> 6, l = t & 63;
    if (l == 0) rm[w] = m;
    __syncthreads();
    m = fmaxf(fmaxf(rm[0], rm[1]), fmaxf(rm[2], rm[3]));
    float sum = 0.f;
    #pragma unroll
    for (int i = 0; i < 9; i++) { v[i] = __expf(v[i] - m); sum += v[i]; }
    #pragma unroll
    for (int o = 32; o >= 1; o >>= 1) sum += __shfl_xor(sum, o);
    if (l == 0) rs[w] = sum;
    __syncthreads();
    sum = rs[0] + rs[1] + rs[2] + rs[3];
    float inv = 1.0f / sum;
    #pragma unroll
    for (int i = 0; i < 9; i++) p[t + i * 256] = f2b(v[i] * inv);
}

// ---------------------------------------------------------------------------
// Generic MFMA GEMM:  D[r][cl] = sum_k A[r][k] * B[cl][k]  (+ epilogue)
// Both operands bf16 row-major-in-K. 128x128 tile, BK=64, 4 waves.
// global_load_lds staging with XOR-swizzled global SOURCE (linear LDS dest),
// swizzled ds_read_b128 fragment reads -> bank-conflict-free.
// ---------------------------------------------------------------------------
enum Modes { MQK = 0, MV = 1, MSC = 2, MPV = 3, MG = 4, MF = 5 };

struct GemmArgs {
    const uint16_t* A; const uint16_t* B; void* D;
    long Az, Bz, Dz;              // z strides in elements
    int lda, ldb, ldd, K;
    const float* bias; long biasz;
    const uint16_t* extra; long extraz;   // gate: Ot tensor
    const float* sdev; float smul;        // MQK: scale = sdev[z]*smul
    int p0;                               // MSC/MPV pair-chunk start
};

template<int MODE>
__global__ __launch_bounds__(256)
void gemm_k(GemmArgs p) {
    __shared__ __align__(16) uint8_t As[128 * 128];  // 128 rows x 64 bf16 (128B), swizzled
    __shared__ __align__(16) uint8_t Bs[128 * 128];

    const int t  = threadIdx.x;
    const int l  = t & 63;
    const int w  = t >> 6;
    const int wr = w >> 1;
    const int wc = w & 1;
    const int z  = blockIdx.z;

    const uint16_t* Aab;
    const uint16_t* Bb;
    uint16_t* Dbf = nullptr;
    float*    Df  = nullptr;
    const float* bias = nullptr;
    const uint16_t* extra = nullptr;

    if constexpr (MODE == MSC || MODE == MPV) {
        int pp = p.p0 + z;
        int a = pp >> 2, b = pp & 3;
        int qm = (a == 0) ? 0 : ((a == 1) ? 2 : 1);   // q/v modality per attend
        if constexpr (MODE == MSC) {
            Aab = p.A + (size_t)qm * RALL * CC + (size_t)b * NN * CC;   // Qt
            Bb  = p.B + (size_t)a  * RALL * CC + (size_t)b * NN * CC;   // Ks
            Dbf = (uint16_t*)p.D + (size_t)z * NN * NN;                 // S slot
        } else {
            Aab = p.A + (size_t)z * NN * NN;                            // S slot
            Bb  = p.B + (size_t)qm * CB * CC * NN + (size_t)b * CC * NN;// V
            Dbf = (uint16_t*)p.D + (size_t)a * RALL * CC + (size_t)b * NN * CC; // Ot
        }
    } else {
        Aab = p.A + (size_t)z * p.Az;
        Bb  = p.B + (size_t)z * p.Bz;
        if constexpr (MODE == MF) Df = (float*)p.D + (size_t)z * p.Dz;
        else                      Dbf = (uint16_t*)p.D + (size_t)z * p.Dz;
        if (p.bias) bias = p.bias + (size_t)z * p.biasz;
        if constexpr (MODE == MG) extra = p.extra + (size_t)z * p.extraz;
    }

    const int lda = p.lda, ldb = p.ldb, ldd = p.ldd;
    const long tR = (long)blockIdx.x * 128;
    const long tC = (long)blockIdx.y * 128;

    // staging: wave w stages rows [w*32, w*32+32) of each 128-row tile.
    // lds linear off = w*4096 + q*1024 + l*16 -> (row = w*32+q*8+(l>>3), inner=(l&7)*16)
    // source inner byte = inner ^ ((row&7)<<4); row&7 == (l>>3)&7
    const int swz = ((l & 7) ^ ((l >> 3) & 7)) * 8;   // elements
    const uint16_t* sA = Aab + (size_t)(tR + w * 32 + (l >> 3)) * lda + swz;
    const uint16_t* sB = Bb  + (size_t)(tC + w * 32 + (l >> 3)) * ldb + swz;

    auto* As3 = (__attribute__((address_space(3))) uint8_t*)As;
    auto* Bs3 = (__attribute__((address_space(3))) uint8_t*)Bs;

    f32x4 acc[4][4];
    #pragma unroll
    for (int i = 0; i < 4; i++)
        #pragma unroll
        for (int j = 0; j < 4; j++) {
            f32x4 zz = {0.f, 0.f, 0.f, 0.f};
            acc[i][j] = zz;
        }

    const int nk = p.K >> 6;
    for (int kt = 0; kt < nk; ++kt) {
        #pragma unroll
        for (int q = 0; q < 4; q++) {
            __builtin_amdgcn_global_load_lds(
                (__attribute__((address_space(1))) void*)(sA + (size_t)q * 8 * lda),
                (__attribute__((address_space(3))) void*)(As3 + w * 4096 + q * 1024),
                16, 0, 0);
            __builtin_amdgcn_global_load_lds(
                (__attribute__((address_space(1))) void*)(sB + (size_t)q * 8 * ldb),
                (__attribute__((address_space(3))) void*)(Bs3 + w * 4096 + q * 1024),
                16, 0, 0);
        }
        sA += 64; sB += 64;
        __syncthreads();   // compiler drains vmcnt(0) before s_barrier

        #pragma unroll
        for (int kk = 0; kk < 2; kk++) {
            short8v af[4], bfv[4];
            #pragma unroll
            for (int i = 0; i < 4; i++) {
                int rowA = wr * 64 + i * 16 + (l & 15);
                int offA = rowA * 128 + ((kk * 64 + ((l >> 4) << 4)) ^ ((rowA & 7) << 4));
                af[i] = *(const short8v*)(As + offA);
                int rowB = wc * 64 + i * 16 + (l & 15);
                int offB = rowB * 128 + ((kk * 64 + ((l >> 4) << 4)) ^ ((rowB & 7) << 4));
                bfv[i] = *(const short8v*)(Bs + offB);
            }
            #pragma unroll
            for (int i = 0; i < 4; i++)
                #pragma unroll
                for (int j = 0; j < 4; j++)
                    acc[i][j] = __builtin_amdgcn_mfma_f32_16x16x32_bf16(
                        af[i], bfv[j], acc[i][j], 0, 0, 0);
        }
        __syncthreads();
    }

    float scale = 1.0f;
    if constexpr (MODE == MQK) scale = p.sdev[z] * p.smul;

    const int rq = (l >> 4) << 2;
    const int cq = l & 15;
    #pragma unroll
    for (int i = 0; i < 4; i++) {
        #pragma unroll
        for (int j = 0; j < 4; j++) {
            long col = tC + wc * 64 + j * 16 + cq;
            #pragma unroll
            for (int r4 = 0; r4 < 4; r4++) {
                long row = tR + wr * 64 + i * 16 + rq + r4;
                float v = acc[i][j][r4];
                if constexpr (MODE == MQK) {
                    Dbf[row * ldd + col] = f2b((v + bias[col]) * scale);
                } else if constexpr (MODE == MV) {
                    Dbf[row * ldd + col] = f2b(v + bias[row]);
                } else if constexpr (MODE == MSC || MODE == MPV) {
                    Dbf[row * ldd + col] = f2b(v);
                } else if constexpr (MODE == MG) {
                    float g = v + bias[col];
                    float sig = 1.0f / (1.0f + __expf(-g));
                    Dbf[row * ldd + col] = f2b(sig * b2f(extra[row * ldd + col]));
                } else { // MF
                    Df[row * ldd + col] = v + bias[row];
                }
            }
        }
    }
}

// ---------------------------------------------------------------------------
// Host
// ---------------------------------------------------------------------------
extern "C" void kernel_launch(void* const* d_in, const int* in_sizes, int n_in,
                              void* d_out, int out_size, void* d_ws, size_t ws_size,
                              hipStream_t stream) {
    const float* x0   = (const float*)d_in[0];
    const float* x1   = (const float*)d_in[1];
    const float* x2   = (const float*)d_in[2];
    const float* sdev = (const float*)d_in[3];

    uint8_t* ws = (uint8_t*)d_ws;
    const size_t off_W  = 0;                           // 11*65536*2 = 1441792
    const size_t off_Bp = 1441792;                     // 11*256*4  = 11264
    const size_t off_Xt = 1453312;                     // 256-aligned
    // ROUND-5 FIX: each of Xt/Qt/Kt/Ks/V holds THREE [9216][256] bf16 slices
    // (per-modality or per-attend). Round-3 advanced offsets by ONE slice
    // (4.72 MB) -> Qt overlapped Xt[mod1] -> total corruption (absmax 0.116).
    const size_t TEN    = (size_t)3 * RALL * CC * 2;   // 14155776 B per buffer
    const size_t off_Qt = off_Xt + TEN;
    const size_t off_Kt = off_Qt + TEN;
    const size_t off_Ks = off_Kt + TEN;
    const size_t off_V  = off_Ks + TEN;
    const size_t off_S  = off_V + TEN;                 // 72232192
    const size_t s_pair = (size_t)NN * NN * 2;         // 10616832

    uint16_t* Wbf = (uint16_t*)(ws + off_W);
    float*    Bpk = (float*)(ws + off_Bp);
    uint16_t* Xt  = (uint16_t*)(ws + off_Xt);
    uint16_t* Qt  = (uint16_t*)(ws + off_Qt);
    uint16_t* Kt  = (uint16_t*)(ws + off_Kt);
    uint16_t* Ks  = (uint16_t*)(ws + off_Ks);
    uint16_t* V   = (uint16_t*)(ws + off_V);
    uint16_t* Ot    = Xt;   // alias: Xt dead after V convs (3 slices fit)
    uint16_t* gated = Kt;   // alias: Kt dead after ksum (3 slices fit)
    uint16_t* fused = Ks;   // alias: Ks dead after last scores GEMM (1 slice)
    float* out = (float*)d_out;

    // S region: dedicated past off_S if workspace allows; else alias onto Kt
    // (Kt dead after ksum; S dead before gated is written; one 10.6 MB pair
    // fits Kt's 14.16 MB).
    size_t fit = (ws_size > off_S) ? (ws_size - off_S) / s_pair : 0;
    int g = (int)(fit > 12 ? 12 : fit);
    uint16_t* S = (g >= 1) ? (uint16_t*)(ws + off_S) : Kt;
    if (g < 1) g = 1;

    // 1. transpose+convert x -> Xt bf16 [mod][b*N+n][c]
    transpose_k<<<dim3(72, 8, 12), dim3(32, 32), 0, stream>>>(x0, x1, x2, Xt);

    // 2. pack weights + biases
    PackPtrs pp;
    const int wIdx[11] = {4, 6, 8, 10, 12, 14, 16, 18, 20, 22, 24};
    for (int j = 0; j < 11; j++) {
        pp.w[j]    = (const float*)d_in[wIdx[j]];
        pp.bsrc[j] = (const float*)d_in[wIdx[j] + 1];
    }
    pack_k<<<dim3(33, 11), 256, 0, stream>>>(pp, Wbf, Bpk);

    // 3. Q convs: Qt[n][o] = (Xt . Wq^T + bq) * s[mod]/16
    {
        GemmArgs a{};
        a.A = Xt;  a.Az = (long)RALL * CC; a.lda = CC;
        a.B = Wbf; a.Bz = 3 * 65536;       a.ldb = CC;
        a.D = Qt;  a.Dz = (long)RALL * CC; a.ldd = CC;
        a.K = CC; a.bias = Bpk; a.biasz = 3 * 256;
        a.sdev = sdev; a.smul = 0.0625f;
        gemm_k<MQK><<<dim3(72, 2, 3), 256, 0, stream>>>(a);
        // 4. K convs: Kt[n][o] = (Xt . Wk^T + bk) * s[mod]
        a.B = Wbf + 65536; a.D = Kt; a.bias = Bpk + 256; a.smul = 1.0f;
        gemm_k<MQK><<<dim3(72, 2, 3), 256, 0, stream>>>(a);
    }

    // 5. V convs: V[mod][b][o][n] = Wv . x + bv
    for (int m = 0; m < 3; m++) {
        GemmArgs a{};
        a.A = Wbf + (size_t)(2 + 3 * m) * 65536; a.Az = 0;              a.lda = CC;
        a.B = Xt + (size_t)m * RALL * CC;        a.Bz = (long)NN * CC;  a.ldb = CC;
        a.D = V + (size_t)m * CB * CC * NN;      a.Dz = (long)CC * NN;  a.ldd = NN;
        a.K = CC; a.bias = Bpk + (2 + 3 * m) * 256; a.biasz = 0;
        gemm_k<MV><<<dim3(2, 18, 4), 256, 0, stream>>>(a);
    }

    // 6. Ks sums
    ksum_k<<<dim3(2304, 3), 256, 0, stream>>>(Kt, Ks);

    // 7. attention: scores -> softmax -> PV, chunked over the 12 (attend,batch)
    for (int p0 = 0; p0 < 12; p0 += g) {
        int gc = (12 - p0 < g) ? (12 - p0) : g;
        GemmArgs sc{};
        sc.A = Qt; sc.B = Ks; sc.D = S; sc.p0 = p0;
        sc.lda = CC; sc.ldb = CC; sc.ldd = NN; sc.K = CC;
        gemm_k<MSC><<<dim3(18, 18, gc), 256, 0, stream>>>(sc);

        softmax_k<<<dim3(2304, gc), 256, 0, stream>>>(S);

        GemmArgs pv{};
        pv.A = S; pv.B = V; pv.D = Ot; pv.p0 = p0;
        pv.lda = NN; pv.ldb = NN; pv.ldd = CC; pv.K = NN;
        gemm_k<MPV><<<dim3(18, 2, gc), 256, 0, stream>>>(pv);
    }

    // 8. gate conv: gated[a][n][o] = sigmoid(Ot.Wg^T + bg) * Ot
    {
        GemmArgs a{};
        a.A = Ot;    a.Az = (long)RALL * CC; a.lda = CC;
        a.B = Wbf + (size_t)9 * 65536; a.Bz = 0; a.ldb = CC;
        a.D = gated; a.Dz = (long)RALL * CC; a.ldd = CC;
        a.K = CC; a.bias = Bpk + 9 * 256; a.biasz = 0;
        a.extra = Ot; a.extraz = (long)RALL * CC;
        gemm_k<MG><<<dim3(72, 2, 3), 256, 0, stream>>>(a);
    }

    // 9. fuse
    fuse_k<<<dim3(2304), 256, 0, stream>>>(gated, fused);

    // 10. final conv -> d_out fp32 [b][o][n]
    {
        GemmArgs a{};
        a.A = Wbf + (size_t)10 * 65536; a.Az = 0; a.lda = CC;
        a.B = fused; a.Bz = (long)NN * CC; a.ldb = CC;
        a.D = out;   a.Dz = (long)CC * NN; a.ldd = NN;
        a.K = CC; a.bias = Bpk + 10 * 256; a.biasz = 0;
        gemm_k<MF><<<dim3(2, 18, 4), 256, 0, stream>>>(a);
    }
}

// Round 7
// 360.593 us; speedup vs baseline: 1.0234x; 1.0234x over previous
//
#include <hip/hip_runtime.h>
#include <cstdint>
#include <cstddef>

#define DEVINL __device__ __forceinline__

typedef __attribute__((ext_vector_type(8))) short short8v;   // 8 bf16 (4 VGPRs)
typedef __attribute__((ext_vector_type(4))) float f32x4;

static constexpr int CB   = 4;       // batches
static constexpr int CC   = 256;     // channels
static constexpr int NN   = 2304;    // H*W
static constexpr int RALL = CB * NN; // 9216

// ---- bf16 helpers (bit-level, RNE; avoids hip_bf16 API drift) ----
DEVINL uint16_t f2b(float f) {
    uint32_t u = __builtin_bit_cast(uint32_t, f);
    u = (u + 0x7FFFu + ((u >> 16) & 1u)) >> 16;
    return (uint16_t)u;
}
DEVINL float b2f(uint16_t u) {
    return __builtin_bit_cast(float, (uint32_t)u << 16);
}

// ---------------------------------------------------------------------------
// Transpose+convert: x[b][c][n] fp32 -> Xt[mod][b*N+n][c] bf16
// ---------------------------------------------------------------------------
__global__ __launch_bounds__(1024)
void transpose_k(const float* __restrict__ x0, const float* __restrict__ x1,
                 const float* __restrict__ x2, uint16_t* __restrict__ Xt) {
    int mod = blockIdx.z >> 2;
    int b   = blockIdx.z & 3;
    const float* x = (mod == 0) ? x0 : ((mod == 1) ? x1 : x2);
    __shared__ float tile[32][33];
    int n0 = blockIdx.x * 32, c0 = blockIdx.y * 32;
    int tx = threadIdx.x, ty = threadIdx.y;
    tile[ty][tx] = x[((size_t)b * CC + c0 + ty) * NN + n0 + tx];
    __syncthreads();
    float v = tile[tx][ty]; // = x[b][c0+tx][n0+ty]
    Xt[(size_t)mod * RALL * CC + ((size_t)b * NN + n0 + ty) * CC + c0 + tx] = f2b(v);
}

// ---------------------------------------------------------------------------
// Pack 11 weight matrices (fp32->bf16, row-major kept) + 11 biases (fp32)
// order: wq0,wk0,wv0,wq1,wk1,wv1,wq2,wk2,wv2,wg,wo
// ---------------------------------------------------------------------------
struct PackPtrs { const float* w[11]; const float* bsrc[11]; };

__global__ __launch_bounds__(256)
void pack_k(PackPtrs pp, uint16_t* __restrict__ Wbf, float* __restrict__ Bpk) {
    int j = blockIdx.y;
    if (blockIdx.x == 32) {
        Bpk[j * 256 + threadIdx.x] = pp.bsrc[j][threadIdx.x];
    } else {
        int base = blockIdx.x * 2048 + threadIdx.x * 8;
        const float* src = pp.w[j] + base;
        uint16_t* dst = Wbf + (size_t)j * 65536 + base;
        #pragma unroll
        for (int i = 0; i < 8; i++) dst[i] = f2b(src[i]);
    }
}

// ---------------------------------------------------------------------------
// Ks[a] = Kt[m1] + Kt[m2]   (a=0: kd+kt ; a=1: kr+kt ; a=2: kr+kd)
// ---------------------------------------------------------------------------
__global__ __launch_bounds__(256)
void ksum_k(const uint16_t* __restrict__ Kt, uint16_t* __restrict__ Ks) {
    int a = blockIdx.y;
    int m1 = (a == 0) ? 2 : 0;
    int m2 = (a == 2) ? 2 : 1;
    size_t idx = ((size_t)blockIdx.x * 256 + threadIdx.x) * 4;
    const uint16_t* p1 = Kt + (size_t)m1 * RALL * CC + idx;
    const uint16_t* p2 = Kt + (size_t)m2 * RALL * CC + idx;
    uint16_t* pd = Ks + (size_t)a * RALL * CC + idx;
    #pragma unroll
    for (int i = 0; i < 4; i++) pd[i] = f2b(b2f(p1[i]) + b2f(p2[i]));
}

// ---------------------------------------------------------------------------
// fused = gated[0] + gated[1] + gated[2]   (bf16)
// ---------------------------------------------------------------------------
__global__ __launch_bounds__(256)
void fuse_k(const uint16_t* __restrict__ gated, uint16_t* __restrict__ fused) {
    size_t idx = ((size_t)blockIdx.x * 256 + threadIdx.x) * 4;
    #pragma unroll
    for (int i = 0; i < 4; i++) {
        float v = b2f(gated[idx + i])
                + b2f(gated[(size_t)RALL * CC + idx + i])
                + b2f(gated[(size_t)2 * RALL * CC + idx + i]);
        fused[idx + i] = f2b(v);
    }
}

// ---------------------------------------------------------------------------
// Generic MFMA GEMM:  D[r][cl] = sum_k A[r][k] * B[cl][k]  (+ epilogue)
// Both operands bf16 row-major-in-K. 128x128 tile, BK=64, 4 waves.
// global_load_lds staging with XOR-swizzled global SOURCE (linear LDS dest),
// swizzled ds_read_b128 fragment reads -> bank-conflict-free.
//
// ROUND-6: softmax kernel eliminated. MSC writes P=exp(s) (unnormalized,
// scores bounded ~|s|<12 so fp32 exp safe) + per-row atomic partial sums
// into rsum[z][n]; MPV epilogue multiplies by 1/rsum[n]. Saves the 254 MB
// softmax HBM round-trip + one dispatch.
// ---------------------------------------------------------------------------
enum Modes { MQK = 0, MV = 1, MSC = 2, MPV = 3, MG = 4, MF = 5 };

struct GemmArgs {
    const uint16_t* A; const uint16_t* B; void* D;
    long Az, Bz, Dz;              // z strides in elements
    int lda, ldb, ldd, K;
    const float* bias; long biasz;
    const uint16_t* extra; long extraz;   // gate: Ot tensor
    const float* sdev; float smul;        // MQK: scale = sdev[z]*smul
    float* rsum;                          // MSC/MPV: row sums [z][NN]
    int p0;                               // MSC/MPV pair-chunk start
};

template<int MODE>
__global__ __launch_bounds__(256)
void gemm_k(GemmArgs p) {
    __shared__ __align__(16) uint8_t As[128 * 128];  // 128 rows x 64 bf16 (128B), swizzled
    __shared__ __align__(16) uint8_t Bs[128 * 128];

    const int t  = threadIdx.x;
    const int l  = t & 63;
    const int w  = t >> 6;
    const int wr = w >> 1;
    const int wc = w & 1;
    const int z  = blockIdx.z;

    const uint16_t* Aab;
    const uint16_t* Bb;
    uint16_t* Dbf = nullptr;
    float*    Df  = nullptr;
    const float* bias = nullptr;
    const uint16_t* extra = nullptr;
    float* rsum = nullptr;

    if constexpr (MODE == MSC || MODE == MPV) {
        int pp = p.p0 + z;
        int a = pp >> 2, b = pp & 3;
        int qm = (a == 0) ? 0 : ((a == 1) ? 2 : 1);   // q/v modality per attend
        rsum = p.rsum + (size_t)z * NN;
        if constexpr (MODE == MSC) {
            Aab = p.A + (size_t)qm * RALL * CC + (size_t)b * NN * CC;   // Qt
            Bb  = p.B + (size_t)a  * RALL * CC + (size_t)b * NN * CC;   // Ks
            Dbf = (uint16_t*)p.D + (size_t)z * NN * NN;                 // S slot
        } else {
            Aab = p.A + (size_t)z * NN * NN;                            // S slot
            Bb  = p.B + (size_t)qm * CB * CC * NN + (size_t)b * CC * NN;// V
            Dbf = (uint16_t*)p.D + (size_t)a * RALL * CC + (size_t)b * NN * CC; // Ot
        }
    } else {
        Aab = p.A + (size_t)z * p.Az;
        Bb  = p.B + (size_t)z * p.Bz;
        if constexpr (MODE == MF) Df = (float*)p.D + (size_t)z * p.Dz;
        else                      Dbf = (uint16_t*)p.D + (size_t)z * p.Dz;
        if (p.bias) bias = p.bias + (size_t)z * p.biasz;
        if constexpr (MODE == MG) extra = p.extra + (size_t)z * p.extraz;
    }

    const int lda = p.lda, ldb = p.ldb, ldd = p.ldd;
    const long tR = (long)blockIdx.x * 128;
    const long tC = (long)blockIdx.y * 128;

    // staging: wave w stages rows [w*32, w*32+32) of each 128-row tile.
    // lds linear off = w*4096 + q*1024 + l*16 -> (row = w*32+q*8+(l>>3), inner=(l&7)*16)
    // source inner byte = inner ^ ((row&7)<<4); row&7 == (l>>3)&7
    const int swz = ((l & 7) ^ ((l >> 3) & 7)) * 8;   // elements
    const uint16_t* sA = Aab + (size_t)(tR + w * 32 + (l >> 3)) * lda + swz;
    const uint16_t* sB = Bb  + (size_t)(tC + w * 32 + (l >> 3)) * ldb + swz;

    auto* As3 = (__attribute__((address_space(3))) uint8_t*)As;
    auto* Bs3 = (__attribute__((address_space(3))) uint8_t*)Bs;

    f32x4 acc[4][4];
    #pragma unroll
    for (int i = 0; i < 4; i++)
        #pragma unroll
        for (int j = 0; j < 4; j++) {
            f32x4 zz = {0.f, 0.f, 0.f, 0.f};
            acc[i][j] = zz;
        }

    const int nk = p.K >> 6;
    for (int kt = 0; kt < nk; ++kt) {
        #pragma unroll
        for (int q = 0; q < 4; q++) {
            __builtin_amdgcn_global_load_lds(
                (__attribute__((address_space(1))) void*)(sA + (size_t)q * 8 * lda),
                (__attribute__((address_space(3))) void*)(As3 + w * 4096 + q * 1024),
                16, 0, 0);
            __builtin_amdgcn_global_load_lds(
                (__attribute__((address_space(1))) void*)(sB + (size_t)q * 8 * ldb),
                (__attribute__((address_space(3))) void*)(Bs3 + w * 4096 + q * 1024),
                16, 0, 0);
        }
        sA += 64; sB += 64;
        __syncthreads();   // compiler drains vmcnt(0) before s_barrier

        #pragma unroll
        for (int kk = 0; kk < 2; kk++) {
            short8v af[4], bfv[4];
            #pragma unroll
            for (int i = 0; i < 4; i++) {
                int rowA = wr * 64 + i * 16 + (l & 15);
                int offA = rowA * 128 + ((kk * 64 + ((l >> 4) << 4)) ^ ((rowA & 7) << 4));
                af[i] = *(const short8v*)(As + offA);
                int rowB = wc * 64 + i * 16 + (l & 15);
                int offB = rowB * 128 + ((kk * 64 + ((l >> 4) << 4)) ^ ((rowB & 7) << 4));
                bfv[i] = *(const short8v*)(Bs + offB);
            }
            #pragma unroll
            for (int i = 0; i < 4; i++)
                #pragma unroll
                for (int j = 0; j < 4; j++)
                    acc[i][j] = __builtin_amdgcn_mfma_f32_16x16x32_bf16(
                        af[i], bfv[j], acc[i][j], 0, 0, 0);
        }
        __syncthreads();
    }

    float scale = 1.0f;
    if constexpr (MODE == MQK) scale = p.sdev[z] * p.smul;

    const int rq = (l >> 4) << 2;
    const int cq = l & 15;
    #pragma unroll
    for (int i = 0; i < 4; i++) {
        #pragma unroll
        for (int r4 = 0; r4 < 4; r4++) {
            long row = tR + wr * 64 + i * 16 + rq + r4;
            if constexpr (MODE == MSC) {
                // P = exp(score), unnormalized; accumulate row partials.
                float part = 0.f;
                #pragma unroll
                for (int j = 0; j < 4; j++) {
                    long col = tC + wc * 64 + j * 16 + cq;
                    float e = __expf(acc[i][j][r4]);
                    part += e;
                    Dbf[row * ldd + col] = f2b(e);
                }
                // row's 64 cols in this wave live in the 16 lanes sharing l>>4
                part += __shfl_xor(part, 1);
                part += __shfl_xor(part, 2);
                part += __shfl_xor(part, 4);
                part += __shfl_xor(part, 8);
                if ((l & 15) == 0) atomicAdd(&rsum[row], part);
            } else if constexpr (MODE == MPV) {
                float inv = 1.0f / rsum[row];
                #pragma unroll
                for (int j = 0; j < 4; j++) {
                    long col = tC + wc * 64 + j * 16 + cq;
                    Dbf[row * ldd + col] = f2b(acc[i][j][r4] * inv);
                }
            } else {
                #pragma unroll
                for (int j = 0; j < 4; j++) {
                    long col = tC + wc * 64 + j * 16 + cq;
                    float v = acc[i][j][r4];
                    if constexpr (MODE == MQK) {
                        Dbf[row * ldd + col] = f2b((v + bias[col]) * scale);
                    } else if constexpr (MODE == MV) {
                        Dbf[row * ldd + col] = f2b(v + bias[row]);
                    } else if constexpr (MODE == MG) {
                        float g = v + bias[col];
                        float sig = 1.0f / (1.0f + __expf(-g));
                        Dbf[row * ldd + col] = f2b(sig * b2f(extra[row * ldd + col]));
                    } else { // MF
                        Df[row * ldd + col] = v + bias[row];
                    }
                }
            }
        }
    }
}

// ---------------------------------------------------------------------------
// Host
// ---------------------------------------------------------------------------
extern "C" void kernel_launch(void* const* d_in, const int* in_sizes, int n_in,
                              void* d_out, int out_size, void* d_ws, size_t ws_size,
                              hipStream_t stream) {
    const float* x0   = (const float*)d_in[0];
    const float* x1   = (const float*)d_in[1];
    const float* x2   = (const float*)d_in[2];
    const float* sdev = (const float*)d_in[3];

    uint8_t* ws = (uint8_t*)d_ws;
    const size_t off_W  = 0;                           // 11*65536*2 = 1441792
    const size_t off_Bp = 1441792;                     // 11*256*4  = 11264
    const size_t off_Xt = 1453312;                     // 256-aligned
    const size_t TEN    = (size_t)3 * RALL * CC * 2;   // 14155776 B per 3-slice buffer
    const size_t off_Qt = off_Xt + TEN;
    const size_t off_Kt = off_Qt + TEN;
    const size_t off_Ks = off_Kt + TEN;
    const size_t off_V  = off_Ks + TEN;
    const size_t off_R  = off_V + TEN;                 // 72232192: rowsum [12][NN] f32
    const size_t off_S  = off_R + (size_t)12 * NN * 4; // 72342784
    const size_t s_pair = (size_t)NN * NN * 2;         // 10616832

    uint16_t* Wbf = (uint16_t*)(ws + off_W);
    float*    Bpk = (float*)(ws + off_Bp);
    uint16_t* Xt  = (uint16_t*)(ws + off_Xt);
    uint16_t* Qt  = (uint16_t*)(ws + off_Qt);
    uint16_t* Kt  = (uint16_t*)(ws + off_Kt);
    uint16_t* Ks  = (uint16_t*)(ws + off_Ks);
    uint16_t* V   = (uint16_t*)(ws + off_V);
    float*    Rs  = (float*)(ws + off_R);
    uint16_t* Ot    = Xt;   // alias: Xt dead after V convs (3 slices fit)
    uint16_t* gated = Kt;   // alias: Kt dead after ksum (3 slices fit)
    uint16_t* fused = Ks;   // alias: Ks dead after last scores GEMM (1 slice)
    float* out = (float*)d_out;

    // S region: dedicated past off_S if workspace allows; else alias onto Kt
    // (Kt dead after ksum; S dead before gated is written; one 10.6 MB pair
    // fits Kt's 14.16 MB).
    size_t fit = (ws_size > off_S) ? (ws_size - off_S) / s_pair : 0;
    int g = (int)(fit > 12 ? 12 : fit);
    uint16_t* S = (g >= 1) ? (uint16_t*)(ws + off_S) : Kt;
    if (g < 1) g = 1;

    // 1. transpose+convert x -> Xt bf16 [mod][b*N+n][c]
    transpose_k<<<dim3(72, 8, 12), dim3(32, 32), 0, stream>>>(x0, x1, x2, Xt);

    // 2. pack weights + biases
    PackPtrs pp;
    const int wIdx[11] = {4, 6, 8, 10, 12, 14, 16, 18, 20, 22, 24};
    for (int j = 0; j < 11; j++) {
        pp.w[j]    = (const float*)d_in[wIdx[j]];
        pp.bsrc[j] = (const float*)d_in[wIdx[j] + 1];
    }
    pack_k<<<dim3(33, 11), 256, 0, stream>>>(pp, Wbf, Bpk);

    // 3. Q convs: Qt[n][o] = (Xt . Wq^T + bq) * s[mod]/16
    {
        GemmArgs a{};
        a.A = Xt;  a.Az = (long)RALL * CC; a.lda = CC;
        a.B = Wbf; a.Bz = 3 * 65536;       a.ldb = CC;
        a.D = Qt;  a.Dz = (long)RALL * CC; a.ldd = CC;
        a.K = CC; a.bias = Bpk; a.biasz = 3 * 256;
        a.sdev = sdev; a.smul = 0.0625f;
        gemm_k<MQK><<<dim3(72, 2, 3), 256, 0, stream>>>(a);
        // 4. K convs: Kt[n][o] = (Xt . Wk^T + bk) * s[mod]
        a.B = Wbf + 65536; a.D = Kt; a.bias = Bpk + 256; a.smul = 1.0f;
        gemm_k<MQK><<<dim3(72, 2, 3), 256, 0, stream>>>(a);
    }

    // 5. V convs: V[mod][b][o][n] = Wv . x + bv
    for (int m = 0; m < 3; m++) {
        GemmArgs a{};
        a.A = Wbf + (size_t)(2 + 3 * m) * 65536; a.Az = 0;              a.lda = CC;
        a.B = Xt + (size_t)m * RALL * CC;        a.Bz = (long)NN * CC;  a.ldb = CC;
        a.D = V + (size_t)m * CB * CC * NN;      a.Dz = (long)CC * NN;  a.ldd = NN;
        a.K = CC; a.bias = Bpk + (2 + 3 * m) * 256; a.biasz = 0;
        gemm_k<MV><<<dim3(2, 18, 4), 256, 0, stream>>>(a);
    }

    // 6. Ks sums
    ksum_k<<<dim3(2304, 3), 256, 0, stream>>>(Kt, Ks);

    // 7. attention: scores+exp+rowsum -> PV(normalize), chunked over 12 pairs
    for (int p0 = 0; p0 < 12; p0 += g) {
        int gc = (12 - p0 < g) ? (12 - p0) : g;
        hipMemsetAsync(Rs, 0, (size_t)gc * NN * 4, stream);

        GemmArgs sc{};
        sc.A = Qt; sc.B = Ks; sc.D = S; sc.p0 = p0; sc.rsum = Rs;
        sc.lda = CC; sc.ldb = CC; sc.ldd = NN; sc.K = CC;
        gemm_k<MSC><<<dim3(18, 18, gc), 256, 0, stream>>>(sc);

        GemmArgs pv{};
        pv.A = S; pv.B = V; pv.D = Ot; pv.p0 = p0; pv.rsum = Rs;
        pv.lda = NN; pv.ldb = NN; pv.ldd = CC; pv.K = NN;
        gemm_k<MPV><<<dim3(18, 2, gc), 256, 0, stream>>>(pv);
    }

    // 8. gate conv: gated[a][n][o] = sigmoid(Ot.Wg^T + bg) * Ot
    {
        GemmArgs a{};
        a.A = Ot;    a.Az = (long)RALL * CC; a.lda = CC;
        a.B = Wbf + (size_t)9 * 65536; a.Bz = 0; a.ldb = CC;
        a.D = gated; a.Dz = (long)RALL * CC; a.ldd = CC;
        a.K = CC; a.bias = Bpk + 9 * 256; a.biasz = 0;
        a.extra = Ot; a.extraz = (long)RALL * CC;
        gemm_k<MG><<<dim3(72, 2, 3), 256, 0, stream>>>(a);
    }

    // 9. fuse
    fuse_k<<<dim3(2304), 256, 0, stream>>>(gated, fused);

    // 10. final conv -> d_out fp32 [b][o][n]
    {
        GemmArgs a{};
        a.A = Wbf + (size_t)10 * 65536; a.Az = 0; a.lda = CC;
        a.B = fused; a.Bz = (long)NN * CC; a.ldb = CC;
        a.D = out;   a.Dz = (long)CC * NN; a.ldd = NN;
        a.K = CC; a.bias = Bpk + 10 * 256; a.biasz = 0;
        gemm_k<MF><<<dim3(2, 18, 4), 256, 0, stream>>>(a);
    }
}

// Round 8
// 317.935 us; speedup vs baseline: 1.1607x; 1.1342x over previous
//
#include <hip/hip_runtime.h>
#include <cstdint>
#include <cstddef>

#define DEVINL __device__ __forceinline__
#define AS1 __attribute__((address_space(1)))
#define AS3 __attribute__((address_space(3)))
#define GLOAD16(src, dst) __builtin_amdgcn_global_load_lds((AS1 void*)(src), (AS3 void*)(dst), 16, 0, 0)

typedef __attribute__((ext_vector_type(8))) short short8v;   // 8 bf16 (4 VGPRs)
typedef __attribute__((ext_vector_type(4))) float f32x4;

static constexpr int CB   = 4;       // batches
static constexpr int CC   = 256;     // channels
static constexpr int NN   = 2304;    // H*W
static constexpr int RALL = CB * NN; // 9216

// ---- bf16 helpers ----
DEVINL uint16_t f2b(float f) {
    uint32_t u = __builtin_bit_cast(uint32_t, f);
    u = (u + 0x7FFFu + ((u >> 16) & 1u)) >> 16;
    return (uint16_t)u;
}
DEVINL float b2f(uint16_t u) {
    return __builtin_bit_cast(float, (uint32_t)u << 16);
}

// ---------------------------------------------------------------------------
// Transpose+convert: x[b][c][n] fp32 -> Xt[mod][b*N+n][c] bf16
// ---------------------------------------------------------------------------
__global__ __launch_bounds__(1024)
void transpose_k(const float* __restrict__ x0, const float* __restrict__ x1,
                 const float* __restrict__ x2, uint16_t* __restrict__ Xt) {
    int mod = blockIdx.z >> 2;
    int b   = blockIdx.z & 3;
    const float* x = (mod == 0) ? x0 : ((mod == 1) ? x1 : x2);
    __shared__ float tile[32][33];
    int n0 = blockIdx.x * 32, c0 = blockIdx.y * 32;
    int tx = threadIdx.x, ty = threadIdx.y;
    tile[ty][tx] = x[((size_t)b * CC + c0 + ty) * NN + n0 + tx];
    __syncthreads();
    float v = tile[tx][ty];
    Xt[(size_t)mod * RALL * CC + ((size_t)b * NN + n0 + ty) * CC + c0 + tx] = f2b(v);
}

// ---------------------------------------------------------------------------
// Pack 11 weight matrices (fp32->bf16) + 11 biases (fp32)
// order: wq0,wk0,wv0,wq1,wk1,wv1,wq2,wk2,wv2,wg,wo
// ---------------------------------------------------------------------------
struct PackPtrs { const float* w[11]; const float* bsrc[11]; };

__global__ __launch_bounds__(256)
void pack_k(PackPtrs pp, uint16_t* __restrict__ Wbf, float* __restrict__ Bpk) {
    int j = blockIdx.y;
    if (blockIdx.x == 32) {
        Bpk[j * 256 + threadIdx.x] = pp.bsrc[j][threadIdx.x];
    } else {
        int base = blockIdx.x * 2048 + threadIdx.x * 8;
        const float* src = pp.w[j] + base;
        uint16_t* dst = Wbf + (size_t)j * 65536 + base;
        #pragma unroll
        for (int i = 0; i < 8; i++) dst[i] = f2b(src[i]);
    }
}

// ---------------------------------------------------------------------------
// Ks[a] = Kt[m1] + Kt[m2]   (a=0: kd+kt ; a=1: kr+kt ; a=2: kr+kd)
// ---------------------------------------------------------------------------
__global__ __launch_bounds__(256)
void ksum_k(const uint16_t* __restrict__ Kt, uint16_t* __restrict__ Ks) {
    int a = blockIdx.y;
    int m1 = (a == 0) ? 2 : 0;
    int m2 = (a == 2) ? 2 : 1;
    size_t idx = ((size_t)blockIdx.x * 256 + threadIdx.x) * 4;
    const uint16_t* p1 = Kt + (size_t)m1 * RALL * CC + idx;
    const uint16_t* p2 = Kt + (size_t)m2 * RALL * CC + idx;
    uint16_t* pd = Ks + (size_t)a * RALL * CC + idx;
    #pragma unroll
    for (int i = 0; i < 4; i++) pd[i] = f2b(b2f(p1[i]) + b2f(p2[i]));
}

// ---------------------------------------------------------------------------
// fused = gated[0] + gated[1] + gated[2]   (bf16)
// ---------------------------------------------------------------------------
__global__ __launch_bounds__(256)
void fuse_k(const uint16_t* __restrict__ gated, uint16_t* __restrict__ fused) {
    size_t idx = ((size_t)blockIdx.x * 256 + threadIdx.x) * 4;
    #pragma unroll
    for (int i = 0; i < 4; i++) {
        float v = b2f(gated[idx + i])
                + b2f(gated[(size_t)RALL * CC + idx + i])
                + b2f(gated[(size_t)2 * RALL * CC + idx + i]);
        fused[idx + i] = f2b(v);
    }
}

// ---------------------------------------------------------------------------
// ROUND-8: strip-structured scores kernel.
// One block = 128 q-rows x ALL 2304 m-cols for one (attend,batch) pair.
// Q staged once to LDS (4 subtiles [128][64]); Ks m-tiles (64 rows x 256 ch,
// 4 subtiles [64][64]) double-buffered with issue-early prefetch (2-phase:
// stage next -> compute cur -> 1 barrier). Epilogue: P=exp(s) -> S (bf16),
// rowsum accumulated in registers (block owns rows exclusively -> no atomics).
// ---------------------------------------------------------------------------
__global__ __launch_bounds__(512)
void msc_k(const uint16_t* __restrict__ Qt, const uint16_t* __restrict__ Ksg,
           uint16_t* __restrict__ S, float* __restrict__ Rs, int p0) {
    __shared__ __align__(16) uint8_t Qs[65536];      // 4 subtiles [128][64]e
    __shared__ __align__(16) uint8_t Kb[65536];      // 2 bufs x 4 subtiles [64][64]e

    const int t = threadIdx.x, l = t & 63, w = t >> 6;
    const int wr = w >> 1, wc = w & 1;               // wave grid 4(q) x 2(m)
    const int z = blockIdx.z;
    const int pp = p0 + z;
    const int a = pp >> 2, b = pp & 3;
    const int qm = (a == 0) ? 0 : ((a == 1) ? 2 : 1);

    const uint16_t* Qb = Qt + (size_t)qm * RALL * CC + (size_t)b * NN * CC
                            + (size_t)blockIdx.x * 128 * CC;
    const uint16_t* Kg = Ksg + (size_t)a * RALL * CC + (size_t)b * NN * CC;
    uint16_t* Sg = S + (size_t)z * NN * NN + (size_t)blockIdx.x * 128 * NN;
    float*    Rg = Rs + (size_t)z * NN + blockIdx.x * 128;

    auto* QsL = (AS3 uint8_t*)Qs;
    auto* KbL = (AS3 uint8_t*)Kb;

    // ---- prologue: stage Q (once) + Ks tile 0 into buf 0 ----
    {
        #pragma unroll
        for (int st = 0; st < 4; ++st)
            #pragma unroll
            for (int it = 0; it < 2; ++it) {
                int o = it * 8192 + t * 16;
                int row = o >> 7, slot = (o >> 4) & 7;
                GLOAD16(Qb + (size_t)row * CC + st * 64 + (slot ^ (row & 7)) * 8,
                        QsL + st * 16384 + o);
            }
        int row = t >> 3, slot = t & 7;
        #pragma unroll
        for (int st = 0; st < 4; ++st)
            GLOAD16(Kg + (size_t)row * CC + st * 64 + (slot ^ (row & 7)) * 8,
                    KbL + st * 8192 + t * 16);
    }
    __syncthreads();

    float rsum[2][4];
    #pragma unroll
    for (int i = 0; i < 2; ++i)
        #pragma unroll
        for (int r4 = 0; r4 < 4; ++r4) rsum[i][r4] = 0.f;

    int cbuf = 0;
    for (int mt = 0; mt < 36; ++mt) {
        // issue prefetch of next Ks tile (completes at this iter's barrier)
        if (mt + 1 < 36) {
            int row = t >> 3, slot = t & 7;
            #pragma unroll
            for (int st = 0; st < 4; ++st)
                GLOAD16(Kg + (size_t)(mt + 1) * 64 * CC + (size_t)row * CC
                           + st * 64 + (slot ^ (row & 7)) * 8,
                        KbL + (cbuf ^ 1) * 32768 + st * 8192 + t * 16);
        }
        // compute S-tile 128q x 64m, K=256
        f32x4 acc2[2][2];
        #pragma unroll
        for (int i = 0; i < 2; ++i)
            #pragma unroll
            for (int j = 0; j < 2; ++j) {
                f32x4 zz = {0.f, 0.f, 0.f, 0.f};
                acc2[i][j] = zz;
            }
        #pragma unroll
        for (int ks = 0; ks < 8; ++ks) {
            int st = ks >> 1, kk = ks & 1;
            short8v qa[2], kb2[2];
            #pragma unroll
            for (int i = 0; i < 2; ++i) {
                int rowA = wr * 32 + i * 16 + (l & 15);
                qa[i] = *(const short8v*)(Qs + st * 16384 + rowA * 128
                          + ((kk * 64 + (l >> 4) * 16) ^ ((rowA & 7) << 4)));
                int rowB = wc * 32 + i * 16 + (l & 15);
                kb2[i] = *(const short8v*)(Kb + cbuf * 32768 + st * 8192 + rowB * 128
                          + ((kk * 64 + (l >> 4) * 16) ^ ((rowB & 7) << 4)));
            }
            #pragma unroll
            for (int i = 0; i < 2; ++i)
                #pragma unroll
                for (int j = 0; j < 2; ++j)
                    acc2[i][j] = __builtin_amdgcn_mfma_f32_16x16x32_bf16(
                        qa[i], kb2[j], acc2[i][j], 0, 0, 0);
        }
        // epilogue: exp -> S, accumulate rowsum in registers
        {
            int rq = (l >> 4) << 2, cq = l & 15;
            #pragma unroll
            for (int i = 0; i < 2; ++i)
                #pragma unroll
                for (int r4 = 0; r4 < 4; ++r4) {
                    int rl = wr * 32 + i * 16 + rq + r4;
                    #pragma unroll
                    for (int j = 0; j < 2; ++j) {
                        float e = __expf(acc2[i][j][r4]);
                        rsum[i][r4] += e;
                        Sg[(size_t)rl * NN + mt * 64 + wc * 32 + j * 16 + cq] = f2b(e);
                    }
                }
        }
        __syncthreads();   // drains prefetch vmcnt + protects buf reuse
        cbuf ^= 1;
    }

    // ---- rowsum reduction: 16 col-lanes via shfl, wc pair via LDS ----
    float* red = (float*)Qs;   // Qs dead after last barrier
    {
        int rq = (l >> 4) << 2;
        #pragma unroll
        for (int i = 0; i < 2; ++i)
            #pragma unroll
            for (int r4 = 0; r4 < 4; ++r4) {
                float v = rsum[i][r4];
                v += __shfl_xor(v, 1); v += __shfl_xor(v, 2);
                v += __shfl_xor(v, 4); v += __shfl_xor(v, 8);
                if ((l & 15) == 0) red[(wr * 32 + i * 16 + rq + r4) * 2 + wc] = v;
            }
    }
    __syncthreads();
    if (t < 128) Rg[t] = red[t * 2] + red[t * 2 + 1];
}

// ---------------------------------------------------------------------------
// Generic MFMA GEMM:  D[r][cl] = sum_k A[r][k] * B[cl][k]  (+ epilogue)
// 128x128 tile, BK=64, 4 waves. ROUND-8: double-buffered LDS + issue-early
// prefetch (1 barrier per K-step instead of 2).
// ---------------------------------------------------------------------------
enum Modes { MQK = 0, MV = 1, MPV = 3, MG = 4, MF = 5 };

struct GemmArgs {
    const uint16_t* A; const uint16_t* B; void* D; void* D2;
    long Az, Bz, Dz;              // z strides in elements
    int lda, ldb, ldd, K;
    const float* bias;
    const uint16_t* extra; long extraz;   // gate: Ot tensor
    const float* sdev;                    // MQK scales
    const float* rsum;                    // MPV: row sums [z][NN]
    int p0;                               // MPV pair-chunk start
};

template<int MODE>
__global__ __launch_bounds__(256)
void gemm_k(GemmArgs p) {
    __shared__ __align__(16) uint8_t As[32768];  // 2 bufs x 128 rows x 64 bf16
    __shared__ __align__(16) uint8_t Bs[32768];

    const int t  = threadIdx.x;
    const int l  = t & 63;
    const int w  = t >> 6;
    const int wr = w >> 1;
    const int wc = w & 1;
    const int z  = blockIdx.z;

    const uint16_t* Aab;
    const uint16_t* Bb;
    uint16_t* Dbf = nullptr;
    float*    Df  = nullptr;
    const float* bias = nullptr;
    const uint16_t* extra = nullptr;
    const float* rsum = nullptr;
    float scale = 1.0f;

    if constexpr (MODE == MPV) {
        int pp = p.p0 + z;
        int a = pp >> 2, b = pp & 3;
        int qm = (a == 0) ? 0 : ((a == 1) ? 2 : 1);
        rsum = p.rsum + (size_t)z * NN;
        Aab = p.A + (size_t)z * NN * NN;                                // S slot
        Bb  = p.B + (size_t)qm * CB * CC * NN + (size_t)b * CC * NN;    // V
        Dbf = (uint16_t*)p.D + (size_t)a * RALL * CC + (size_t)b * NN * CC; // Ot
    } else if constexpr (MODE == MQK) {
        int mod = z % 3, qk = z / 3;   // qk: 0=Q conv, 1=K conv
        Aab = p.A + (size_t)mod * p.Az;
        Bb  = p.B + (size_t)(mod * 3 + qk) * 65536;
        Dbf = (uint16_t*)(qk ? p.D2 : p.D) + (size_t)mod * p.Dz;
        bias = p.bias + (size_t)(mod * 3 + qk) * 256;
        scale = p.sdev[mod] * (qk ? 1.0f : 0.0625f);
    } else if constexpr (MODE == MV) {
        int mod = z >> 2, bb = z & 3;
        Aab = p.A + (size_t)(2 + 3 * mod) * 65536;                      // Wv
        Bb  = p.B + (size_t)mod * RALL * CC + (size_t)bb * NN * CC;     // Xt
        Dbf = (uint16_t*)p.D + (size_t)mod * CB * CC * NN + (size_t)bb * CC * NN;
        bias = p.bias + (size_t)(2 + 3 * mod) * 256;
    } else {
        Aab = p.A + (size_t)z * p.Az;
        Bb  = p.B + (size_t)z * p.Bz;
        if constexpr (MODE == MF) Df = (float*)p.D + (size_t)z * p.Dz;
        else                      Dbf = (uint16_t*)p.D + (size_t)z * p.Dz;
        if (p.bias) bias = p.bias;
        if constexpr (MODE == MG) extra = p.extra + (size_t)z * p.extraz;
    }

    const int lda = p.lda, ldb = p.ldb, ldd = p.ldd;
    const long tR = (long)blockIdx.x * 128;
    const long tC = (long)blockIdx.y * 128;

    const int swz = ((l & 7) ^ ((l >> 3) & 7)) * 8;   // elements
    const uint16_t* sA = Aab + (size_t)(tR + w * 32 + (l >> 3)) * lda + swz;
    const uint16_t* sB = Bb  + (size_t)(tC + w * 32 + (l >> 3)) * ldb + swz;

    auto* As3 = (AS3 uint8_t*)As;
    auto* Bs3 = (AS3 uint8_t*)Bs;

    f32x4 acc[4][4];
    #pragma unroll
    for (int i = 0; i < 4; i++)
        #pragma unroll
        for (int j = 0; j < 4; j++) {
            f32x4 zz = {0.f, 0.f, 0.f, 0.f};
            acc[i][j] = zz;
        }

    const int nk = p.K >> 6;
    // prologue: stage K-tile 0 into buf 0
    #pragma unroll
    for (int q = 0; q < 4; q++) {
        GLOAD16(sA + (size_t)q * 8 * lda, As3 + w * 4096 + q * 1024);
        GLOAD16(sB + (size_t)q * 8 * ldb, Bs3 + w * 4096 + q * 1024);
    }
    __syncthreads();

    for (int kt = 0; kt < nk; ++kt) {
        const int cb = kt & 1;
        if (kt + 1 < nk) {   // issue prefetch; completes at this iter's barrier
            #pragma unroll
            for (int q = 0; q < 4; q++) {
                GLOAD16(sA + (size_t)(kt + 1) * 64 + (size_t)q * 8 * lda,
                        As3 + (cb ^ 1) * 16384 + w * 4096 + q * 1024);
                GLOAD16(sB + (size_t)(kt + 1) * 64 + (size_t)q * 8 * ldb,
                        Bs3 + (cb ^ 1) * 16384 + w * 4096 + q * 1024);
            }
        }
        #pragma unroll
        for (int kk = 0; kk < 2; kk++) {
            short8v af[4], bfv[4];
            #pragma unroll
            for (int i = 0; i < 4; i++) {
                int rowA = wr * 64 + i * 16 + (l & 15);
                int offA = cb * 16384 + rowA * 128
                         + ((kk * 64 + ((l >> 4) << 4)) ^ ((rowA & 7) << 4));
                af[i] = *(const short8v*)(As + offA);
                int rowB = wc * 64 + i * 16 + (l & 15);
                int offB = cb * 16384 + rowB * 128
                         + ((kk * 64 + ((l >> 4) << 4)) ^ ((rowB & 7) << 4));
                bfv[i] = *(const short8v*)(Bs + offB);
            }
            #pragma unroll
            for (int i = 0; i < 4; i++)
                #pragma unroll
                for (int j = 0; j < 4; j++)
                    acc[i][j] = __builtin_amdgcn_mfma_f32_16x16x32_bf16(
                        af[i], bfv[j], acc[i][j], 0, 0, 0);
        }
        __syncthreads();
    }

    const int rq = (l >> 4) << 2;
    const int cq = l & 15;
    #pragma unroll
    for (int i = 0; i < 4; i++) {
        #pragma unroll
        for (int r4 = 0; r4 < 4; r4++) {
            long row = tR + wr * 64 + i * 16 + rq + r4;
            if constexpr (MODE == MPV) {
                float inv = 1.0f / rsum[row];
                #pragma unroll
                for (int j = 0; j < 4; j++) {
                    long col = tC + wc * 64 + j * 16 + cq;
                    Dbf[row * ldd + col] = f2b(acc[i][j][r4] * inv);
                }
            } else {
                #pragma unroll
                for (int j = 0; j < 4; j++) {
                    long col = tC + wc * 64 + j * 16 + cq;
                    float v = acc[i][j][r4];
                    if constexpr (MODE == MQK) {
                        Dbf[row * ldd + col] = f2b((v + bias[col]) * scale);
                    } else if constexpr (MODE == MV) {
                        Dbf[row * ldd + col] = f2b(v + bias[row]);
                    } else if constexpr (MODE == MG) {
                        float g = v + bias[col];
                        float sig = 1.0f / (1.0f + __expf(-g));
                        Dbf[row * ldd + col] = f2b(sig * b2f(extra[row * ldd + col]));
                    } else { // MF
                        Df[row * ldd + col] = v + bias[row];
                    }
                }
            }
        }
    }
}

// ---------------------------------------------------------------------------
// Host
// ---------------------------------------------------------------------------
extern "C" void kernel_launch(void* const* d_in, const int* in_sizes, int n_in,
                              void* d_out, int out_size, void* d_ws, size_t ws_size,
                              hipStream_t stream) {
    const float* x0   = (const float*)d_in[0];
    const float* x1   = (const float*)d_in[1];
    const float* x2   = (const float*)d_in[2];
    const float* sdev = (const float*)d_in[3];

    uint8_t* ws = (uint8_t*)d_ws;
    const size_t off_W  = 0;
    const size_t off_Bp = 1441792;
    const size_t off_Xt = 1453312;
    const size_t TEN    = (size_t)3 * RALL * CC * 2;   // 14155776 B per 3-slice buffer
    const size_t off_Qt = off_Xt + TEN;
    const size_t off_Kt = off_Qt + TEN;
    const size_t off_Ks = off_Kt + TEN;
    const size_t off_V  = off_Ks + TEN;
    const size_t off_R  = off_V + TEN;                 // rowsum [12][NN] f32
    const size_t off_S  = off_R + (size_t)12 * NN * 4;
    const size_t s_pair = (size_t)NN * NN * 2;

    uint16_t* Wbf = (uint16_t*)(ws + off_W);
    float*    Bpk = (float*)(ws + off_Bp);
    uint16_t* Xt  = (uint16_t*)(ws + off_Xt);
    uint16_t* Qt  = (uint16_t*)(ws + off_Qt);
    uint16_t* Kt  = (uint16_t*)(ws + off_Kt);
    uint16_t* Ks  = (uint16_t*)(ws + off_Ks);
    uint16_t* V   = (uint16_t*)(ws + off_V);
    float*    Rs  = (float*)(ws + off_R);
    uint16_t* Ot    = Xt;   // alias: Xt dead after V convs
    uint16_t* gated = Kt;   // alias: Kt dead after ksum
    uint16_t* fused = Ks;   // alias: Ks dead after last scores pass
    float* out = (float*)d_out;

    size_t fit = (ws_size > off_S) ? (ws_size - off_S) / s_pair : 0;
    int g = (int)(fit > 12 ? 12 : fit);
    uint16_t* S = (g >= 1) ? (uint16_t*)(ws + off_S) : Kt;
    if (g < 1) g = 1;

    // 1. transpose+convert
    transpose_k<<<dim3(72, 8, 12), dim3(32, 32), 0, stream>>>(x0, x1, x2, Xt);

    // 2. pack weights + biases
    PackPtrs pp;
    const int wIdx[11] = {4, 6, 8, 10, 12, 14, 16, 18, 20, 22, 24};
    for (int j = 0; j < 11; j++) {
        pp.w[j]    = (const float*)d_in[wIdx[j]];
        pp.bsrc[j] = (const float*)d_in[wIdx[j] + 1];
    }
    pack_k<<<dim3(33, 11), 256, 0, stream>>>(pp, Wbf, Bpk);

    // 3. Q+K convs merged (z=6: mod = z%3, qk = z/3)
    {
        GemmArgs a{};
        a.A = Xt;  a.Az = (long)RALL * CC; a.lda = CC;
        a.B = Wbf; a.ldb = CC;
        a.D = Qt;  a.D2 = Kt; a.Dz = (long)RALL * CC; a.ldd = CC;
        a.K = CC; a.bias = Bpk; a.sdev = sdev;
        gemm_k<MQK><<<dim3(72, 2, 6), 256, 0, stream>>>(a);
    }

    // 4. V convs merged (z=12: mod = z>>2, b = z&3)
    {
        GemmArgs a{};
        a.A = Wbf; a.lda = CC;
        a.B = Xt;  a.ldb = CC;
        a.D = V;   a.ldd = NN;
        a.K = CC; a.bias = Bpk;
        gemm_k<MV><<<dim3(2, 18, 12), 256, 0, stream>>>(a);
    }

    // 5. Ks sums
    ksum_k<<<dim3(2304, 3), 256, 0, stream>>>(Kt, Ks);

    // 6. attention: strip scores+exp+rowsum -> PV(normalize), chunked
    for (int p0 = 0; p0 < 12; p0 += g) {
        int gc = (12 - p0 < g) ? (12 - p0) : g;

        msc_k<<<dim3(18, 1, gc), 512, 0, stream>>>(Qt, Ks, S, Rs, p0);

        GemmArgs pv{};
        pv.A = S; pv.B = V; pv.D = Ot; pv.p0 = p0; pv.rsum = Rs;
        pv.lda = NN; pv.ldb = NN; pv.ldd = CC; pv.K = NN;
        gemm_k<MPV><<<dim3(18, 2, gc), 256, 0, stream>>>(pv);
    }

    // 7. gate conv
    {
        GemmArgs a{};
        a.A = Ot;    a.Az = (long)RALL * CC; a.lda = CC;
        a.B = Wbf + (size_t)9 * 65536; a.Bz = 0; a.ldb = CC;
        a.D = gated; a.Dz = (long)RALL * CC; a.ldd = CC;
        a.K = CC; a.bias = Bpk + 9 * 256;
        a.extra = Ot; a.extraz = (long)RALL * CC;
        gemm_k<MG><<<dim3(72, 2, 3), 256, 0, stream>>>(a);
    }

    // 8. fuse
    fuse_k<<<dim3(2304), 256, 0, stream>>>(gated, fused);

    // 9. final conv -> d_out fp32 [b][o][n]
    {
        GemmArgs a{};
        a.A = Wbf + (size_t)10 * 65536; a.Az = 0; a.lda = CC;
        a.B = fused; a.Bz = (long)NN * CC; a.ldb = CC;
        a.D = out;   a.Dz = (long)CC * NN; a.ldd = NN;
        a.K = CC; a.bias = Bpk + 10 * 256;
        gemm_k<MF><<<dim3(2, 18, 4), 256, 0, stream>>>(a);
    }
}